// Round 1
// 583.111 us; speedup vs baseline: 1.0346x; 1.0346x over previous
//
#include <hip/hip_runtime.h>
#include <cstdint>
#include <cstddef>

// Problem shape (fixed): B=4, Sq=2048 -> S=8192 tokens, M=1024, E=8, H=4096,
// C=S/E=1024 capacity.
// WS BUDGET: keep total workspace <= ~84 MB (r1 failed post-timing with a
// 218 MB footprint). Do not grow past this without evidence.
// R4 change: GEMMs rewritten from the m97-class 2-barrier structure to the
// 8-phase counted-vmcnt template (T2 swizzle + T3/T4 counted vmcnt + T5
// setprio + T1 XCD/expert affinity). gemm1: 256x256 tile, gemm2: 256x128.
// Raw s_barrier (asm, "memory") in the K-loop -- __syncthreads would inject
// a vmcnt(0) drain and reproduce the ~900TF ceiling.
#define S_TOK 8192
#define MDIM  1024
#define EEXP  8
#define HDIM  4096
#define HHALF 2048
#define CAP   1024

typedef __attribute__((ext_vector_type(8))) short short8v;   // 8 bf16 in 4 VGPRs
typedef __attribute__((ext_vector_type(4))) float f32x4;

__device__ __forceinline__ short f2bf(float f) {
    __bf16 b = (__bf16)f;                 // RNE hardware convert on gfx950
    return __builtin_bit_cast(short, b);
}

__device__ __forceinline__ void gld_lds16(const void* g, void* l) {
    __builtin_amdgcn_global_load_lds(
        (const __attribute__((address_space(1))) void*)g,
        (__attribute__((address_space(3))) void*)l, 16, 0, 0);
}

#define BAR() asm volatile("s_barrier" ::: "memory")
#define WAIT_VM(N) asm volatile("s_waitcnt vmcnt(" #N ")" ::: "memory")

// ---------------------------------------------------------------------------
// K1: gating. One wave per token, fp64 accumulation -> exactly-rounded logits
// so argmax matches the numpy reference. graw = 1/sum(exp(l-m)).
// ---------------------------------------------------------------------------
__global__ void gate_kernel(const float* __restrict__ x, const float* __restrict__ wg,
                            int* __restrict__ eidx, float* __restrict__ graw) {
    const int wave = threadIdx.x >> 6, lane = threadIdx.x & 63;
    const int tok = blockIdx.x * 4 + wave;
    const float* xr = x + (size_t)tok * MDIM;
    double acc[8] = {0, 0, 0, 0, 0, 0, 0, 0};
#pragma unroll
    for (int kk = 0; kk < 16; ++kk) {
        int i = kk * 64 + lane;
        float xv = xr[i];
        float4 w0 = *(const float4*)(wg + (size_t)i * 8);
        float4 w1v = *(const float4*)(wg + (size_t)i * 8 + 4);
        acc[0] += (double)xv * (double)w0.x;
        acc[1] += (double)xv * (double)w0.y;
        acc[2] += (double)xv * (double)w0.z;
        acc[3] += (double)xv * (double)w0.w;
        acc[4] += (double)xv * (double)w1v.x;
        acc[5] += (double)xv * (double)w1v.y;
        acc[6] += (double)xv * (double)w1v.z;
        acc[7] += (double)xv * (double)w1v.w;
    }
#pragma unroll
    for (int off = 32; off >= 1; off >>= 1) {
#pragma unroll
        for (int e = 0; e < 8; ++e) acc[e] += __shfl_down(acc[e], off);
    }
    if (lane == 0) {
        float l[8];
#pragma unroll
        for (int e = 0; e < 8; ++e) l[e] = (float)acc[e];
        float m = l[0]; int best = 0;
#pragma unroll
        for (int e = 1; e < 8; ++e) { if (l[e] > m) { m = l[e]; best = e; } }
        float den = 0.f;
#pragma unroll
        for (int e = 0; e < 8; ++e) den += expf(l[e] - m);
        eidx[tok] = best;
        graw[tok] = 1.0f / den;
    }
}

// ---------------------------------------------------------------------------
// K2: capacity scan. One block; pos[t] = count of earlier same-expert tokens.
// ---------------------------------------------------------------------------
__global__ void scan_kernel(const int* __restrict__ eidx, const float* __restrict__ graw,
                            float* __restrict__ gfin, int* __restrict__ slot_token) {
    __shared__ int cnt[256][8];
    __shared__ int pfx[256][8];
    const int t = threadIdx.x;
    const int base = t * 32;
    int local[8] = {0, 0, 0, 0, 0, 0, 0, 0};
    for (int j = 0; j < 32; ++j) {
        int ev = eidx[base + j];
#pragma unroll
        for (int e = 0; e < 8; ++e) local[e] += (ev == e);
    }
#pragma unroll
    for (int e = 0; e < 8; ++e) cnt[t][e] = local[e];
    __syncthreads();
    if (t < 8) {
        int run = 0;
        for (int i = 0; i < 256; ++i) { pfx[i][t] = run; run += cnt[i][t]; }
    }
    __syncthreads();
    int run[8];
#pragma unroll
    for (int e = 0; e < 8; ++e) run[e] = pfx[t][e];
    for (int j = 0; j < 32; ++j) {
        int tok = base + j;
        int ev = eidx[tok];
        int pos = 0;
#pragma unroll
        for (int e = 0; e < 8; ++e) { if (ev == e) pos = run[e]; run[e] += (ev == e); }
        if (pos < CAP) {
            gfin[tok] = graw[tok];
            slot_token[ev * CAP + pos] = tok;
        } else {
            gfin[tok] = 0.f;
        }
    }
}

// ---------------------------------------------------------------------------
// K3: dispatch — gather kept token rows into bf16 dispA[E*CAP][MDIM].
// ---------------------------------------------------------------------------
__global__ void dispatch_kernel(const float* __restrict__ x, const int* __restrict__ slot_token,
                                short* __restrict__ dispA) {
    const int slot = blockIdx.x;
    const int tok = slot_token[slot];
    const int t = threadIdx.x;
    short4 ov;
    if (tok >= 0) {
        float4 v = *(const float4*)(x + (size_t)tok * MDIM + t * 4);
        ov.x = f2bf(v.x); ov.y = f2bf(v.y); ov.z = f2bf(v.z); ov.w = f2bf(v.w);
    } else {
        ov.x = 0; ov.y = 0; ov.z = 0; ov.w = 0;
    }
    *(short4*)(dispA + (size_t)slot * MDIM + t * 4) = ov;
}

// ---------------------------------------------------------------------------
// K4: fp32 -> bf16 cast + transpose of an [R][C] slab into [C][R] bf16.
// ---------------------------------------------------------------------------
__global__ void cast_transpose_kernel(const float* __restrict__ in, short* __restrict__ out,
                                      int R, int C, int rstride,
                                      size_t in_estride, size_t out_estride) {
    __shared__ float tile[64][65];
    const int e = blockIdx.z;
    const float* src = in + (size_t)e * in_estride;
    short* dst = out + (size_t)e * out_estride;
    const int r0 = blockIdx.x * 64, c0 = blockIdx.y * 64;
    const int t = threadIdx.x;
    const int rr = t >> 4, cq = (t & 15) * 4;
#pragma unroll
    for (int j = 0; j < 4; ++j) {
        int r = rr + j * 16;
        float4 v = *(const float4*)(src + (size_t)(r0 + r) * rstride + c0 + cq);
        tile[r][cq + 0] = v.x; tile[r][cq + 1] = v.y;
        tile[r][cq + 2] = v.z; tile[r][cq + 3] = v.w;
    }
    __syncthreads();
    const int oc = t >> 2, ch = (t & 3) * 16;
    union { short s[16]; int4 v2[2]; } u;
#pragma unroll
    for (int j = 0; j < 16; ++j) u.s[j] = f2bf(tile[ch + j][oc]);
    int4* dp = (int4*)(dst + (size_t)(c0 + oc) * R + r0 + ch);
    dp[0] = u.v2[0]; dp[1] = u.v2[1];
}

// ---------------------------------------------------------------------------
// 8-phase GEMM core (m201-template class), BM=256, BK=64, 8 waves, 512 thr.
//
// LDS layout: A tile [256][64] bf16 (2 buffers), B tile [BN][64] bf16 (2
// buffers), linear rows of 128 B. Read-side bank-conflict swizzle: the 16B
// chunk index within a row is XOR'd with (row&7); the staging pre-applies the
// same XOR to the GLOBAL source column so global_load_lds can stay linear
// (rule 21: both-sides-or-neither).
//
// Staging schedule per tile t (provably race-free with 2 buffers):
//   p0: B0(t+1) -> other buf   (region last read at t-1 p3, barrier since)
//   p1: B1(t+1) -> other buf   (BN==256 only)
//   p2: A0(t+2) -> CURRENT buf (all A frags are register-held by end of p1)
//   p3: A1(t+2) -> CURRENT buf
// Boundary: vmcnt(4) (the two A(t+2) half-tiles stay in flight), vmcnt(0)
// only entering the last tile. Never __syncthreads in the loop.
//
// Fragment maps (HW-verified m89/m91):
//   A: A[m=lane&15][k=(lane>>4)*8+j];  B: Bt[n=lane&15][k=(lane>>4)*8+j]
//   C/D: col=lane&15, row=(lane>>4)*4+reg
// ---------------------------------------------------------------------------
__device__ __forceinline__ void stage_half(const short* __restrict__ g, int K, int k0,
                                           short* ldsdst) {
    // 128 rows x 64 cols bf16; 512 threads x 2 x 16B. LDS dest is wave-uniform
    // base + lane*16 (hardware), i.e. linear [row][64].
    const int t = threadIdx.x;
    const int w = t >> 6, l = t & 63;
    const int rl = l >> 3;                    // row within 8-row group
    const int swz = ((l & 7) ^ rl) * 8;       // pre-swizzled source column
#pragma unroll
    for (int j = 0; j < 2; ++j) {
        const int rg = (j * 8 + w) * 8;
        gld_lds16(g + (size_t)(rg + rl) * K + k0 + swz, ldsdst + rg * 64);
    }
}

__device__ __forceinline__ short8v rdfrag(const short* tile, int row, int kq) {
    // kq = ks*4 + fq : 16B-chunk index within the 128B row
    return *(const short8v*)(tile + row * 64 + ((kq ^ (row & 7)) * 8));
}

#define MMA_QUAD(PROW, BARR, PCOL)                                            \
    __builtin_amdgcn_s_setprio(1);                                            \
    _Pragma("unroll")                                                         \
    for (int i = 0; i < MFh; ++i)                                             \
        _Pragma("unroll")                                                     \
        for (int jj = 0; jj < 2; ++jj)                                        \
            _Pragma("unroll")                                                 \
            for (int ks = 0; ks < 2; ++ks)                                    \
                acc[(PROW) * MFh + i][(PCOL) * 2 + jj] =                      \
                    __builtin_amdgcn_mfma_f32_16x16x32_bf16(                  \
                        a[PROW][ks][i], BARR[ks][jj],                         \
                        acc[(PROW) * MFh + i][(PCOL) * 2 + jj], 0, 0, 0);     \
    __builtin_amdgcn_s_setprio(0);

template <int BN, int K>
__device__ __forceinline__ void gemm8p(const short* __restrict__ A,
                                       const short* __restrict__ B,
                                       int m0, int n0,
                                       short* ldsA, short* ldsB,
                                       f32x4 (&acc)[BN / 32][4]) {
    constexpr int NT  = K / 64;
    constexpr int NWC = BN / 64;   // col-waves: 4 (BN=256) or 2 (BN=128)
    constexpr int WM  = BN / 2;    // per-wave rows: 128 or 64
    constexpr int MFh = BN / 64;   // row-frags per half-phase: 4 or 2
    const int tid = threadIdx.x;
    const int wid = tid >> 6, lane = tid & 63;
    const int wr = wid / NWC, wcn = wid % NWC;
    const int fr = lane & 15, fq = lane >> 4;

    const short* Ab = A + (size_t)m0 * K;
    const short* Bb = B + (size_t)n0 * K;

    // prologue: tile0 (A+B) + tile1 A; leave tile1's A (4 loads) in flight
    stage_half(Ab, K, 0, ldsA);
    stage_half(Ab + (size_t)128 * K, K, 0, ldsA + 128 * 64);
    stage_half(Bb, K, 0, ldsB);
    if constexpr (BN == 256) stage_half(Bb + (size_t)128 * K, K, 0, ldsB + 128 * 64);
    stage_half(Ab, K, 64, ldsA + 256 * 64);
    stage_half(Ab + (size_t)128 * K, K, 64, ldsA + 256 * 64 + 128 * 64);
    WAIT_VM(4);
    BAR();

    for (int t = 0; t < NT; ++t) {
        const short* pA = ldsA + (t & 1) * (256 * 64);
        const short* pB = ldsB + (t & 1) * (BN * 64);
        short* sA = ldsA + (t & 1) * (256 * 64);          // A(t+2) -> current buf
        short* sB = ldsB + ((t + 1) & 1) * (BN * 64);     // B(t+1) -> other buf
        const int kA = (t + 2) * 64, kB = (t + 1) * 64;
        const int rowA = wr * WM;
        const int rowB = wcn * 64;

        short8v a[2][2][MFh];    // [prow][ks][i] — held for the whole tile
        short8v b0[2][2];        // pcol 0 frags
        short8v b1v[2][2];       // pcol 1 frags

        // ---- phase 0: read A(prow0)+B(pcol0) | stage B0(t+1) | MFMA(0,0)
#pragma unroll
        for (int ks = 0; ks < 2; ++ks) {
#pragma unroll
            for (int i = 0; i < MFh; ++i)
                a[0][ks][i] = rdfrag(pA, rowA + i * 16 + fr, ks * 4 + fq);
#pragma unroll
            for (int jj = 0; jj < 2; ++jj)
                b0[ks][jj] = rdfrag(pB, rowB + jj * 16 + fr, ks * 4 + fq);
        }
        if (t + 1 < NT) stage_half(Bb, K, kB, sB);
        BAR();
        MMA_QUAD(0, b0, 0);
        BAR();

        // ---- phase 1: read A(prow1) | stage B1(t+1) | MFMA(1,0)
#pragma unroll
        for (int ks = 0; ks < 2; ++ks)
#pragma unroll
            for (int i = 0; i < MFh; ++i)
                a[1][ks][i] = rdfrag(pA, rowA + WM / 2 + i * 16 + fr, ks * 4 + fq);
        if constexpr (BN == 256) {
            if (t + 1 < NT) stage_half(Bb + (size_t)128 * K, K, kB, sB + 128 * 64);
        }
        BAR();
        MMA_QUAD(1, b0, 0);
        BAR();

        // ---- phase 2: read B(pcol1) | stage A0(t+2) | MFMA(0,1)
#pragma unroll
        for (int ks = 0; ks < 2; ++ks)
#pragma unroll
            for (int jj = 0; jj < 2; ++jj)
                b1v[ks][jj] = rdfrag(pB, rowB + 32 + jj * 16 + fr, ks * 4 + fq);
        if (t + 2 < NT) stage_half(Ab, K, kA, sA);
        BAR();
        MMA_QUAD(0, b1v, 1);
        BAR();

        // ---- phase 3: stage A1(t+2) | MFMA(1,1) | counted boundary wait
        if (t + 2 < NT) stage_half(Ab + (size_t)128 * K, K, kA, sA + 128 * 64);
        BAR();
        MMA_QUAD(1, b1v, 1);
        if (t + 2 < NT) { WAIT_VM(4); } else { WAIT_VM(0); }
        BAR();
    }
}

// Bijective expert->XCD remap: grid is (4,8,8)=256 blocks; blocks with
// lin%8==k (one XCD) become one expert's 32 tiles -> that expert's 4MB weight
// panel lives in that XCD's private L2.
__device__ __forceinline__ int3 remap_block() {
    int lin = blockIdx.x + (blockIdx.y << 2) + (blockIdx.z << 5);
    lin = (lin & 7) * 32 + (lin >> 3);
    int3 r;
    r.z = lin >> 5;          // expert
    r.x = lin & 3;           // m-tile
    r.y = (lin >> 2) & 7;    // n-tile
    return r;
}

// GEMM1 half: h[e,c,n] = relu(dispA[e,c,:].w1t[e,n,:] + b1[e,hoff+n])
__global__ __launch_bounds__(512, 2)
void gemm1_kernel(const short* __restrict__ dispA, const short* __restrict__ w1t,
                  const float* __restrict__ b1, short* __restrict__ h, int hoff) {
    __shared__ alignas(16) short ldsA[2 * 256 * 64];
    __shared__ alignas(16) short ldsB[2 * 256 * 64];
    const int3 bid = remap_block();
    const int e = bid.z;
    const int m0 = bid.x * 256, n0 = bid.y * 256;

    f32x4 acc[8][4];
#pragma unroll
    for (int i = 0; i < 8; ++i)
#pragma unroll
        for (int j = 0; j < 4; ++j) acc[i][j] = (f32x4){0.f, 0.f, 0.f, 0.f};

    gemm8p<256, MDIM>(dispA + (size_t)e * CAP * MDIM,
                      w1t + (size_t)e * HHALF * MDIM, m0, n0, ldsA, ldsB, acc);

    const int wid = threadIdx.x >> 6, lane = threadIdx.x & 63;
    const int wr = wid >> 2, wcn = wid & 3, fr = lane & 15, fq = lane >> 4;
    const float* b1e = b1 + (size_t)e * HDIM + hoff;
    short* hExp = h + (size_t)e * CAP * HHALF;
#pragma unroll
    for (int nf = 0; nf < 4; ++nf) {
        const int gcol = n0 + wcn * 64 + nf * 16 + fr;
        const float bias = b1e[gcol];
#pragma unroll
        for (int mf = 0; mf < 8; ++mf)
#pragma unroll
            for (int r2 = 0; r2 < 4; ++r2) {
                const int grow = m0 + wr * 128 + mf * 16 + fq * 4 + r2;
                float v = acc[mf][nf][r2] + bias;
                hExp[(size_t)grow * HHALF + gcol] = f2bf(v > 0.f ? v : 0.f);
            }
    }
}

// GEMM2 half: eo_part[e,c,m] = h[e,c,:].w2t[e,m,:]; scatter (acc[+b2])*gv.
__global__ __launch_bounds__(512, 2)
void gemm2_kernel(const short* __restrict__ h, const short* __restrict__ w2t,
                  const float* __restrict__ b2, const int* __restrict__ slot_token,
                  const float* __restrict__ gfin, float* __restrict__ out,
                  int acc_flag) {
    __shared__ alignas(16) short ldsA[2 * 256 * 64];
    __shared__ alignas(16) short ldsB[2 * 128 * 64];
    const int3 bid = remap_block();
    const int e = bid.z;
    const int m0 = bid.x * 256, n0 = bid.y * 128;

    f32x4 acc[4][4];
#pragma unroll
    for (int i = 0; i < 4; ++i)
#pragma unroll
        for (int j = 0; j < 4; ++j) acc[i][j] = (f32x4){0.f, 0.f, 0.f, 0.f};

    gemm8p<128, HHALF>(h + (size_t)e * CAP * HHALF,
                       w2t + (size_t)e * MDIM * HHALF, m0, n0, ldsA, ldsB, acc);

    const int wid = threadIdx.x >> 6, lane = threadIdx.x & 63;
    const int wr = wid >> 1, wcn = wid & 1, fr = lane & 15, fq = lane >> 4;
    const float* b2e = b2 + (size_t)e * MDIM;
#pragma unroll
    for (int mf = 0; mf < 4; ++mf)
#pragma unroll
        for (int r2 = 0; r2 < 4; ++r2) {
            const int grow = m0 + wr * 64 + mf * 16 + fq * 4 + r2;
            const int tok = slot_token[e * CAP + grow];
            if (tok < 0) continue;
            const float gv = gfin[tok];
            float* orow = out + (size_t)tok * MDIM;
            if (acc_flag == 0) {
#pragma unroll
                for (int nf = 0; nf < 4; ++nf) {
                    const int gcol = n0 + wcn * 64 + nf * 16 + fr;
                    orow[gcol] = (acc[mf][nf][r2] + b2e[gcol]) * gv;
                }
            } else {
#pragma unroll
                for (int nf = 0; nf < 4; ++nf) {
                    const int gcol = n0 + wcn * 64 + nf * 16 + fr;
                    orow[gcol] += acc[mf][nf][r2] * gv;
                }
            }
        }
}

// ---------------------------------------------------------------------------
// Workspace layout (bytes) — TOTAL 84,017,152 B (~80.1 MiB):
//   wt    bf16 [E][2048][1024] ping-pong :        0 .. 33,554,432
//   hbuf  bf16 [E][C][HHALF]             : 33,554,432 .. 67,108,864
//   dispA bf16 [E*C][M]                  : 67,108,864 .. 83,886,080
//   eidx/graw/gfin/slot_token            : 83,886,080 .. 84,017,152
// ---------------------------------------------------------------------------
extern "C" void kernel_launch(void* const* d_in, const int* in_sizes, int n_in,
                              void* d_out, int out_size, void* d_ws, size_t ws_size,
                              hipStream_t stream) {
    const float* x  = (const float*)d_in[0];
    const float* wg = (const float*)d_in[1];
    const float* w1 = (const float*)d_in[2];
    const float* b1 = (const float*)d_in[3];
    const float* w2 = (const float*)d_in[4];
    const float* b2 = (const float*)d_in[5];
    float* out = (float*)d_out;

    char* ws = (char*)d_ws;
    short* wt    = (short*)(ws);
    short* hbuf  = (short*)(ws + 33554432);
    short* dispA = (short*)(ws + 67108864);
    int*   eidx  = (int*)  (ws + 83886080);
    float* graw  = (float*)(ws + 83886080 + 32768);
    float* gfin  = (float*)(ws + 83886080 + 65536);
    int*   slot_token = (int*)(ws + 83886080 + 98304);

    hipMemsetAsync(slot_token, 0xFF, S_TOK * sizeof(int), stream);       // -1
    hipMemsetAsync(d_out, 0, (size_t)out_size * sizeof(float), stream);  // dropped tokens -> 0

    gate_kernel<<<S_TOK / 4, 256, 0, stream>>>(x, wg, eidx, graw);
    scan_kernel<<<1, 256, 0, stream>>>(eidx, graw, gfin, slot_token);
    dispatch_kernel<<<EEXP * CAP, 256, 0, stream>>>(x, slot_token, dispA);

    for (int half = 0; half < 2; ++half) {
        // w1 slab: in [E][M][H], rows r=M (stride H), cols c = hoff..hoff+2048
        cast_transpose_kernel<<<dim3(MDIM / 64, HHALF / 64, EEXP), 256, 0, stream>>>(
            w1 + (size_t)half * HHALF, wt, MDIM, HHALF, HDIM,
            (size_t)MDIM * HDIM, (size_t)HHALF * MDIM);
        gemm1_kernel<<<dim3(4, 8, 8), 512, 0, stream>>>(
            dispA, wt, b1, hbuf, half * HHALF);
        // w2 slab: in [E][H][M], rows r = hoff..hoff+2048 (stride M), cols c=M
        cast_transpose_kernel<<<dim3(HHALF / 64, MDIM / 64, EEXP), 256, 0, stream>>>(
            w2 + (size_t)half * HHALF * MDIM, wt, HHALF, MDIM, MDIM,
            (size_t)HDIM * MDIM, (size_t)MDIM * HHALF);
        gemm2_kernel<<<dim3(4, 8, 8), 512, 0, stream>>>(
            hbuf, wt, b2, slot_token, gfin, out, half);
    }
}

// Round 2
// 577.582 us; speedup vs baseline: 1.0445x; 1.0096x over previous
//
#include <hip/hip_runtime.h>
#include <cstdint>
#include <cstddef>

// Problem shape (fixed): B=4, Sq=2048 -> S=8192 tokens, M=1024, E=8, H=4096,
// C=S/E=1024 capacity.
// WS BUDGET: keep total workspace <= ~84 MB.
// R5 change: GEMM LDS is now two K-PANELS per 64-k tile ([rows][32] bf16,
// 64B rows). Phases ordered by ks consume panels in staging order ->
// distance-1 prefetch for BOTH operands into the other buffer, counted
// vmcnt(4)/vmcnt(3) before phase-ending barriers (vmcnt(0) only at the last
// tile). No frag lives past its phase: gemm1 regs ~190 (R4 held all A frags
// across the tile -> ~255 + spill, which is why R4 only gained 20us).
// 64B rows also hit the LDS bank floor with NO swizzle.
#define S_TOK 8192
#define MDIM  1024
#define EEXP  8
#define HDIM  4096
#define HHALF 2048
#define CAP   1024

typedef __attribute__((ext_vector_type(8))) short short8v;   // 8 bf16 in 4 VGPRs
typedef __attribute__((ext_vector_type(4))) float f32x4;

__device__ __forceinline__ short f2bf(float f) {
    __bf16 b = (__bf16)f;                 // RNE hardware convert on gfx950
    return __builtin_bit_cast(short, b);
}

__device__ __forceinline__ void gld_lds16(const void* g, void* l) {
    __builtin_amdgcn_global_load_lds(
        (const __attribute__((address_space(1))) void*)g,
        (__attribute__((address_space(3))) void*)l, 16, 0, 0);
}

#define BAR() asm volatile("s_barrier" ::: "memory")
#define WAIT_VM(N) asm volatile("s_waitcnt vmcnt(" #N ")" ::: "memory")

// ---------------------------------------------------------------------------
// K1: gating. One wave per token, fp64 accumulation -> exactly-rounded logits
// so argmax matches the numpy reference. graw = 1/sum(exp(l-m)).
// ---------------------------------------------------------------------------
__global__ void gate_kernel(const float* __restrict__ x, const float* __restrict__ wg,
                            int* __restrict__ eidx, float* __restrict__ graw) {
    const int wave = threadIdx.x >> 6, lane = threadIdx.x & 63;
    const int tok = blockIdx.x * 4 + wave;
    const float* xr = x + (size_t)tok * MDIM;
    double acc[8] = {0, 0, 0, 0, 0, 0, 0, 0};
#pragma unroll
    for (int kk = 0; kk < 16; ++kk) {
        int i = kk * 64 + lane;
        float xv = xr[i];
        float4 w0 = *(const float4*)(wg + (size_t)i * 8);
        float4 w1v = *(const float4*)(wg + (size_t)i * 8 + 4);
        acc[0] += (double)xv * (double)w0.x;
        acc[1] += (double)xv * (double)w0.y;
        acc[2] += (double)xv * (double)w0.z;
        acc[3] += (double)xv * (double)w0.w;
        acc[4] += (double)xv * (double)w1v.x;
        acc[5] += (double)xv * (double)w1v.y;
        acc[6] += (double)xv * (double)w1v.z;
        acc[7] += (double)xv * (double)w1v.w;
    }
#pragma unroll
    for (int off = 32; off >= 1; off >>= 1) {
#pragma unroll
        for (int e = 0; e < 8; ++e) acc[e] += __shfl_down(acc[e], off);
    }
    if (lane == 0) {
        float l[8];
#pragma unroll
        for (int e = 0; e < 8; ++e) l[e] = (float)acc[e];
        float m = l[0]; int best = 0;
#pragma unroll
        for (int e = 1; e < 8; ++e) { if (l[e] > m) { m = l[e]; best = e; } }
        float den = 0.f;
#pragma unroll
        for (int e = 0; e < 8; ++e) den += expf(l[e] - m);
        eidx[tok] = best;
        graw[tok] = 1.0f / den;
    }
}

// ---------------------------------------------------------------------------
// K2: capacity scan. One block; pos[t] = count of earlier same-expert tokens.
// ---------------------------------------------------------------------------
__global__ void scan_kernel(const int* __restrict__ eidx, const float* __restrict__ graw,
                            float* __restrict__ gfin, int* __restrict__ slot_token) {
    __shared__ int cnt[256][8];
    __shared__ int pfx[256][8];
    const int t = threadIdx.x;
    const int base = t * 32;
    int local[8] = {0, 0, 0, 0, 0, 0, 0, 0};
    for (int j = 0; j < 32; ++j) {
        int ev = eidx[base + j];
#pragma unroll
        for (int e = 0; e < 8; ++e) local[e] += (ev == e);
    }
#pragma unroll
    for (int e = 0; e < 8; ++e) cnt[t][e] = local[e];
    __syncthreads();
    if (t < 8) {
        int run = 0;
        for (int i = 0; i < 256; ++i) { pfx[i][t] = run; run += cnt[i][t]; }
    }
    __syncthreads();
    int run[8];
#pragma unroll
    for (int e = 0; e < 8; ++e) run[e] = pfx[t][e];
    for (int j = 0; j < 32; ++j) {
        int tok = base + j;
        int ev = eidx[tok];
        int pos = 0;
#pragma unroll
        for (int e = 0; e < 8; ++e) { if (ev == e) pos = run[e]; run[e] += (ev == e); }
        if (pos < CAP) {
            gfin[tok] = graw[tok];
            slot_token[ev * CAP + pos] = tok;
        } else {
            gfin[tok] = 0.f;
        }
    }
}

// ---------------------------------------------------------------------------
// K3: dispatch — gather kept token rows into bf16 dispA[E*CAP][MDIM].
// ---------------------------------------------------------------------------
__global__ void dispatch_kernel(const float* __restrict__ x, const int* __restrict__ slot_token,
                                short* __restrict__ dispA) {
    const int slot = blockIdx.x;
    const int tok = slot_token[slot];
    const int t = threadIdx.x;
    short4 ov;
    if (tok >= 0) {
        float4 v = *(const float4*)(x + (size_t)tok * MDIM + t * 4);
        ov.x = f2bf(v.x); ov.y = f2bf(v.y); ov.z = f2bf(v.z); ov.w = f2bf(v.w);
    } else {
        ov.x = 0; ov.y = 0; ov.z = 0; ov.w = 0;
    }
    *(short4*)(dispA + (size_t)slot * MDIM + t * 4) = ov;
}

// ---------------------------------------------------------------------------
// K4: fp32 -> bf16 cast + transpose of an [R][C] slab into [C][R] bf16.
// ---------------------------------------------------------------------------
__global__ void cast_transpose_kernel(const float* __restrict__ in, short* __restrict__ out,
                                      int R, int C, int rstride,
                                      size_t in_estride, size_t out_estride) {
    __shared__ float tile[64][65];
    const int e = blockIdx.z;
    const float* src = in + (size_t)e * in_estride;
    short* dst = out + (size_t)e * out_estride;
    const int r0 = blockIdx.x * 64, c0 = blockIdx.y * 64;
    const int t = threadIdx.x;
    const int rr = t >> 4, cq = (t & 15) * 4;
#pragma unroll
    for (int j = 0; j < 4; ++j) {
        int r = rr + j * 16;
        float4 v = *(const float4*)(src + (size_t)(r0 + r) * rstride + c0 + cq);
        tile[r][cq + 0] = v.x; tile[r][cq + 1] = v.y;
        tile[r][cq + 2] = v.z; tile[r][cq + 3] = v.w;
    }
    __syncthreads();
    const int oc = t >> 2, ch = (t & 3) * 16;
    union { short s[16]; int4 v2[2]; } u;
#pragma unroll
    for (int j = 0; j < 16; ++j) u.s[j] = f2bf(tile[ch + j][oc]);
    int4* dp = (int4*)(dst + (size_t)(c0 + oc) * R + r0 + ch);
    dp[0] = u.v2[0]; dp[1] = u.v2[1];
}

// ---------------------------------------------------------------------------
// GEMM core, k-panel 8-phase variant. BM=256, BK=64 as 2 k-panels of 32.
//
// LDS per operand: [2 buf][2 ks][ROWS][32] bf16, 64B rows. A = 64 KiB;
// B = 64 KiB (BN=256) or 32 KiB (BN=128). A frag read (ds_read_b128) has its
// 4 fq lane-groups covering each 64B row fully -> bank-floor, no swizzle.
//
// Phase = (ks, prow): 16 MFMA, 4 A frags (+4 B frags at prow==0). Staging per
// phase targets buffer (t+1)&1 (last read ended at tile t-1's final barrier):
//   gemm1 (4 phases): p0:Ak0  p1:Bk0  p2:Ak1  p3:Bk1
//   gemm2 (2 phases): p0:Ak0+Bk0      p1:Ak1+Bk1
// Counted waits BEFORE the phase-ending barrier (per-wave vmcnt + barrier =
// collective guarantee): end of each ks-group, WAIT_VM(4) [gemm1: 2+2 loads
// of the newer ks-group stay in flight] / WAIT_VM(3) [gemm2: 2+1]. Last tile
// (no prefetch issued) degrades to WAIT_VM(0) or the old panels never drain.
//
// Fragment maps (HW-verified m89/m91):
//   A: A[m=lane&15][k=(lane>>4)*8+j];  B: Bt[n=lane&15][k=(lane>>4)*8+j]
//   C/D: col=lane&15, row=(lane>>4)*4+reg
// ---------------------------------------------------------------------------
template <int ROWS>
__device__ __forceinline__ void stage_panel(const short* __restrict__ g, int K, int k0,
                                            short* lds) {
    // ROWS x 32 bf16 panel, rows 64B: 4 lanes/row, wave covers 16 rows.
    const int t = threadIdx.x, w = t >> 6, l = t & 63;
    const int r = l >> 2, c = (l & 3) * 8;
#pragma unroll
    for (int j = 0; j < ROWS / 128; ++j) {
        const int rg = j * 128 + w * 16;
        gld_lds16(g + (size_t)(rg + r) * K + k0 + c, lds + rg * 32);
    }
}

__device__ __forceinline__ short8v rdpanel(const short* panel, int row, int fq) {
    return *(const short8v*)(panel + row * 32 + fq * 8);
}

template <int BN, int K>
__device__ __forceinline__ void gemm_core(const short* __restrict__ A,
                                          const short* __restrict__ B,
                                          int m0, int n0,
                                          short* __restrict__ ldsA,
                                          short* __restrict__ ldsB,
                                          f32x4 (&acc)[BN / 32][4]) {
    constexpr int NT    = K / 64;
    constexpr int NWC   = BN / 64;       // col-waves: 4 (BN=256) or 2 (BN=128)
    constexpr int WM    = 32 * NWC;      // per-wave rows: 128 or 64
    constexpr int NPROW = WM / 64;       // prow phases per ks: 2 or 1
    const int tid = threadIdx.x;
    const int wid = tid >> 6, lane = tid & 63;
    const int wr = wid / NWC, wcn = wid % NWC;
    const int fr = lane & 15, fq = lane >> 4;
    const int rowA0 = wr * WM;
    const int rowB0 = wcn * 64;

    const short* Ab = A + (size_t)m0 * K;
    const short* Bb = B + (size_t)n0 * K;

    // prologue: all 4 panels of tile 0; leave the ks1 panels in flight.
    stage_panel<256>(Ab, K, 0, ldsA);
    stage_panel<BN >(Bb, K, 0, ldsB);
    stage_panel<256>(Ab, K, 32, ldsA + 256 * 32);
    stage_panel<BN >(Bb, K, 32, ldsB + BN * 32);
    if constexpr (BN == 256) { WAIT_VM(4); } else { WAIT_VM(3); }
    BAR();

    for (int t = 0; t < NT; ++t) {
        const int buf = t & 1, obuf = buf ^ 1;
        const short* bA = ldsA + buf * (2 * 256 * 32);
        const short* bB = ldsB + buf * (2 * BN * 32);
        short* sA = ldsA + obuf * (2 * 256 * 32);
        short* sB = ldsB + obuf * (2 * BN * 32);
        const int kn = (t + 1) * 64;
        const bool pf = (t + 1 < NT);

#pragma unroll
        for (int ks = 0; ks < 2; ++ks) {
            const short* pA = bA + ks * (256 * 32);
            const short* pB = bB + ks * (BN * 32);
            short8v bv[4];
#pragma unroll
            for (int j = 0; j < 4; ++j)
                bv[j] = rdpanel(pB, rowB0 + j * 16 + fr, fq);
#pragma unroll
            for (int prow = 0; prow < NPROW; ++prow) {
                short8v av[4];
#pragma unroll
                for (int i = 0; i < 4; ++i)
                    av[i] = rdpanel(pA, rowA0 + prow * 64 + i * 16 + fr, fq);

                if constexpr (NPROW == 2) {
                    // 4 phases: p0:Ak0(t+1) p1:Bk0 p2:Ak1 p3:Bk1
                    if (pf) {
                        if (prow == 0) stage_panel<256>(Ab, K, kn + ks * 32,
                                                        sA + ks * 256 * 32);
                        else           stage_panel<BN >(Bb, K, kn + ks * 32,
                                                        sB + ks * BN * 32);
                    }
                    if (prow == NPROW - 1) {
                        if (pf) { WAIT_VM(4); } else { WAIT_VM(0); }
                    }
                } else {
                    // 2 phases: p0:Ak0+Bk0(t+1) p1:Ak1+Bk1
                    if (pf) {
                        stage_panel<256>(Ab, K, kn + ks * 32, sA + ks * 256 * 32);
                        stage_panel<BN >(Bb, K, kn + ks * 32, sB + ks * BN * 32);
                    }
                    if (pf) { WAIT_VM(3); } else { WAIT_VM(0); }
                }
                BAR();
                __builtin_amdgcn_s_setprio(1);
#pragma unroll
                for (int i = 0; i < 4; ++i)
#pragma unroll
                    for (int j = 0; j < 4; ++j)
                        acc[prow * 4 + i][j] = __builtin_amdgcn_mfma_f32_16x16x32_bf16(
                            av[i], bv[j], acc[prow * 4 + i][j], 0, 0, 0);
                __builtin_amdgcn_s_setprio(0);
                BAR();
            }
        }
    }
}

// Bijective expert->XCD remap: grid is (4,8,8)=256 blocks; blocks with
// lin%8==k (one XCD) become one expert's 32 tiles -> that expert's weight
// panel lives in that XCD's private L2.
__device__ __forceinline__ int3 remap_block() {
    int lin = blockIdx.x + (blockIdx.y << 2) + (blockIdx.z << 5);
    lin = (lin & 7) * 32 + (lin >> 3);
    int3 r;
    r.z = lin >> 5;          // expert
    r.x = lin & 3;           // m-tile
    r.y = (lin >> 2) & 7;    // n-tile
    return r;
}

// GEMM1 half: h[e,c,n] = relu(dispA[e,c,:].w1t[e,n,:] + b1[e,hoff+n])
__global__ __launch_bounds__(512, 2)
void gemm1_kernel(const short* __restrict__ dispA, const short* __restrict__ w1t,
                  const float* __restrict__ b1, short* __restrict__ h, int hoff) {
    __shared__ alignas(16) short ldsA[2 * 2 * 256 * 32];
    __shared__ alignas(16) short ldsB[2 * 2 * 256 * 32];
    const int3 bid = remap_block();
    const int e = bid.z;
    const int m0 = bid.x * 256, n0 = bid.y * 256;

    f32x4 acc[8][4];
#pragma unroll
    for (int i = 0; i < 8; ++i)
#pragma unroll
        for (int j = 0; j < 4; ++j) acc[i][j] = (f32x4){0.f, 0.f, 0.f, 0.f};

    gemm_core<256, MDIM>(dispA + (size_t)e * CAP * MDIM,
                         w1t + (size_t)e * HHALF * MDIM, m0, n0, ldsA, ldsB, acc);

    const int wid = threadIdx.x >> 6, lane = threadIdx.x & 63;
    const int wr = wid >> 2, wcn = wid & 3, fr = lane & 15, fq = lane >> 4;
    const float* b1e = b1 + (size_t)e * HDIM + hoff;
    short* hExp = h + (size_t)e * CAP * HHALF;
#pragma unroll
    for (int nf = 0; nf < 4; ++nf) {
        const int gcol = n0 + wcn * 64 + nf * 16 + fr;
        const float bias = b1e[gcol];
#pragma unroll
        for (int mf = 0; mf < 8; ++mf)
#pragma unroll
            for (int r2 = 0; r2 < 4; ++r2) {
                const int grow = m0 + wr * 128 + mf * 16 + fq * 4 + r2;
                float v = acc[mf][nf][r2] + bias;
                hExp[(size_t)grow * HHALF + gcol] = f2bf(v > 0.f ? v : 0.f);
            }
    }
}

// GEMM2 half: eo_part[e,c,m] = h[e,c,:].w2t[e,m,:]; scatter (acc[+b2])*gv.
__global__ __launch_bounds__(512, 2)
void gemm2_kernel(const short* __restrict__ h, const short* __restrict__ w2t,
                  const float* __restrict__ b2, const int* __restrict__ slot_token,
                  const float* __restrict__ gfin, float* __restrict__ out,
                  int acc_flag) {
    __shared__ alignas(16) short ldsA[2 * 2 * 256 * 32];
    __shared__ alignas(16) short ldsB[2 * 2 * 128 * 32];
    const int3 bid = remap_block();
    const int e = bid.z;
    const int m0 = bid.x * 256, n0 = bid.y * 128;

    f32x4 acc[4][4];
#pragma unroll
    for (int i = 0; i < 4; ++i)
#pragma unroll
        for (int j = 0; j < 4; ++j) acc[i][j] = (f32x4){0.f, 0.f, 0.f, 0.f};

    gemm_core<128, HHALF>(h + (size_t)e * CAP * HHALF,
                          w2t + (size_t)e * MDIM * HHALF, m0, n0, ldsA, ldsB, acc);

    const int wid = threadIdx.x >> 6, lane = threadIdx.x & 63;
    const int wr = wid >> 1, wcn = wid & 1, fr = lane & 15, fq = lane >> 4;
    const float* b2e = b2 + (size_t)e * MDIM;
#pragma unroll
    for (int mf = 0; mf < 4; ++mf)
#pragma unroll
        for (int r2 = 0; r2 < 4; ++r2) {
            const int grow = m0 + wr * 64 + mf * 16 + fq * 4 + r2;
            const int tok = slot_token[e * CAP + grow];
            if (tok < 0) continue;
            const float gv = gfin[tok];
            float* orow = out + (size_t)tok * MDIM;
            if (acc_flag == 0) {
#pragma unroll
                for (int nf = 0; nf < 4; ++nf) {
                    const int gcol = n0 + wcn * 64 + nf * 16 + fr;
                    orow[gcol] = (acc[mf][nf][r2] + b2e[gcol]) * gv;
                }
            } else {
#pragma unroll
                for (int nf = 0; nf < 4; ++nf) {
                    const int gcol = n0 + wcn * 64 + nf * 16 + fr;
                    orow[gcol] += acc[mf][nf][r2] * gv;
                }
            }
        }
}

// ---------------------------------------------------------------------------
// Workspace layout (bytes) — TOTAL 84,017,152 B (~80.1 MiB):
//   wt    bf16 [E][2048][1024] ping-pong :        0 .. 33,554,432
//   hbuf  bf16 [E][C][HHALF]             : 33,554,432 .. 67,108,864
//   dispA bf16 [E*C][M]                  : 67,108,864 .. 83,886,080
//   eidx/graw/gfin/slot_token            : 83,886,080 .. 84,017,152
// ---------------------------------------------------------------------------
extern "C" void kernel_launch(void* const* d_in, const int* in_sizes, int n_in,
                              void* d_out, int out_size, void* d_ws, size_t ws_size,
                              hipStream_t stream) {
    const float* x  = (const float*)d_in[0];
    const float* wg = (const float*)d_in[1];
    const float* w1 = (const float*)d_in[2];
    const float* b1 = (const float*)d_in[3];
    const float* w2 = (const float*)d_in[4];
    const float* b2 = (const float*)d_in[5];
    float* out = (float*)d_out;

    char* ws = (char*)d_ws;
    short* wt    = (short*)(ws);
    short* hbuf  = (short*)(ws + 33554432);
    short* dispA = (short*)(ws + 67108864);
    int*   eidx  = (int*)  (ws + 83886080);
    float* graw  = (float*)(ws + 83886080 + 32768);
    float* gfin  = (float*)(ws + 83886080 + 65536);
    int*   slot_token = (int*)(ws + 83886080 + 98304);

    hipMemsetAsync(slot_token, 0xFF, S_TOK * sizeof(int), stream);       // -1
    hipMemsetAsync(d_out, 0, (size_t)out_size * sizeof(float), stream);  // dropped tokens -> 0

    gate_kernel<<<S_TOK / 4, 256, 0, stream>>>(x, wg, eidx, graw);
    scan_kernel<<<1, 256, 0, stream>>>(eidx, graw, gfin, slot_token);
    dispatch_kernel<<<EEXP * CAP, 256, 0, stream>>>(x, slot_token, dispA);

    for (int half = 0; half < 2; ++half) {
        // w1 slab: in [E][M][H], rows r=M (stride H), cols c = hoff..hoff+2048
        cast_transpose_kernel<<<dim3(MDIM / 64, HHALF / 64, EEXP), 256, 0, stream>>>(
            w1 + (size_t)half * HHALF, wt, MDIM, HHALF, HDIM,
            (size_t)MDIM * HDIM, (size_t)HHALF * MDIM);
        gemm1_kernel<<<dim3(4, 8, 8), 512, 0, stream>>>(
            dispA, wt, b1, hbuf, half * HHALF);
        // w2 slab: in [E][H][M], rows r = hoff..hoff+2048 (stride M), cols c=M
        cast_transpose_kernel<<<dim3(HHALF / 64, MDIM / 64, EEXP), 256, 0, stream>>>(
            w2 + (size_t)half * HHALF * MDIM, wt, HHALF, MDIM, MDIM,
            (size_t)HDIM * MDIM, (size_t)MDIM * HHALF);
        gemm2_kernel<<<dim3(4, 8, 8), 512, 0, stream>>>(
            hbuf, wt, b2, slot_token, gfin, out, half);
    }
}